// Round 11
// baseline (67732.904 us; speedup 1.0000x reference)
//
#include <hip/hip_runtime.h>
#include <math.h>

#define TSTEPS 1024
#define NXD 128
#define NAD 64
#define NW 32          // workers (one XCD's worth of CUs)
#define TPB 512
#define LSTR 67        // LDS row stride for L
#define QSTR 65        // LDS row stride for staged Qaa
#define KSTR 68        // LDS row stride for K / Qax columns
#define GAINW 129
#define HWREG_XCC_ID 63508   // s_getreg imm: ID=20 (XCC_ID), offset 0, size 32

// ---------- lane-broadcast helpers ----------
__device__ __forceinline__ float rdl(float v, int l) {
  return __int_as_float(__builtin_amdgcn_readlane(__float_as_int(v), l));
}
__device__ __forceinline__ double rdl(double v, int l) {
  unsigned long long b = (unsigned long long)__double_as_longlong(v);
  int lo = __builtin_amdgcn_readlane((int)(b & 0xffffffffULL), l);
  int hi = __builtin_amdgcn_readlane((int)(b >> 32), l);
  unsigned long long r = (((unsigned long long)(unsigned)hi) << 32) | (unsigned)lo;
  return __longlong_as_double((long long)r);
}

// ---------- XCD-local (L2) primitives: atomics execute at L2, never L1 ----------
__device__ __forceinline__ unsigned atomAddL2(unsigned* p, unsigned v) {
  unsigned old;
  asm volatile("global_atomic_add %0, %1, %2, off sc0\n\ts_waitcnt vmcnt(0)"
               : "=v"(old) : "v"(p), "v"(v) : "memory");
  return old;
}
__device__ __forceinline__ void stU32L2(unsigned* p, unsigned v) {
  asm volatile("global_store_dword %0, %1, off sc0\n\ts_waitcnt vmcnt(0)"
               :: "v"(p), "v"(v) : "memory");
}

// ---------- XCD-local barrier: L2 atomics, atomic-RMW poll, bounded + abortable ----
__device__ __forceinline__ bool gbarL2(unsigned* arrive, unsigned* epoch, unsigned* abortW,
                                       unsigned e, volatile int* sAbort) {
  asm volatile("s_waitcnt vmcnt(0)" ::: "memory");   // drain stores to L2 (L1 write-through)
  __syncthreads();
  if (threadIdx.x == 0) {
    *sAbort = 0;
    unsigned prev = atomAddL2(arrive, 1u);
    if (prev == e * NW - 1u) {
      atomAddL2(epoch, 1u);                          // release: epoch e-1 -> e (atomic at L2)
    } else {
      unsigned it = 0;
      for (;;) {
        if (atomAddL2(epoch, 0u) >= e) break;        // atomic read-at-L2, never stale L1
        if ((++it & 255u) == 0u) {
          if (atomAddL2(abortW, 0u) != 0u) { *sAbort = 1; break; }
          if (it > 4000000u) {                       // ~1s: broken sync -> visible abort
            stU32L2(abortW, 1u);
            stU32L2(epoch, 0x7FFFFFFFu);
            *sAbort = 1; break;
          }
        }
        __builtin_amdgcn_s_sleep(1);
      }
    }
  }
  __syncthreads();
  asm volatile("buffer_inv sc0" ::: "memory");       // invalidate L1: plain loads see L2
  return *sAbort == 0;
}

// ---------- unpivoted LDL^T factor, lane = row, regs, reads LDS-staged Qaa ----------
__device__ __forceinline__ float factor32(const float* __restrict__ QaaS, int lane,
                                          float* __restrict__ Lsh) {
  float a[64];
#pragma unroll
  for (int k = 0; k < 64; ++k) a[k] = QaaS[lane * QSTR + k];
  float mmax = 0.f;
#pragma unroll
  for (int j = 0; j < 63; ++j) {
    float d = rdl(a[j], j);
    d = (d == 0.f) ? 1e-30f : d;
    float rdv = 1.0f / d;
    float m = a[j] * rdv;
    m = (lane > j) ? m : 0.f;
    mmax = fmaxf(mmax, fabsf(m));
#pragma unroll
    for (int k = j + 1; k < 64; ++k) {
      float u = rdl(a[j], k);          // = A[k][j] == A[j][k] (symmetric trick)
      a[k] = fmaf(-m, u, a[k]);
    }
    if (lane > j) a[j] = m;
  }
#pragma unroll
  for (int k = 0; k < 64; ++k) Lsh[lane * LSTR + k] = a[k];
#pragma unroll
  for (int s = 1; s < 64; s <<= 1) mmax = fmaxf(mmax, __shfl_xor(mmax, s));
  return mmax;
}

__device__ __forceinline__ void factor64(const float* __restrict__ QaaS, int lane,
                                         double* __restrict__ Lsh) {
  double a[64];
#pragma unroll
  for (int k = 0; k < 64; ++k) a[k] = (double)QaaS[lane * QSTR + k];
#pragma unroll
  for (int j = 0; j < 63; ++j) {
    double d = rdl(a[j], j);
    d = (d == 0.0) ? 1e-300 : d;
    double rdv = 1.0 / d;
    double m = a[j] * rdv;
    m = (lane > j) ? m : 0.0;
#pragma unroll
    for (int k = j + 1; k < 64; ++k) {
      double u = rdl(a[j], k);
      a[k] = fma(-m, u, a[k]);
    }
    if (lane > j) a[j] = m;
  }
#pragma unroll
  for (int k = 0; k < 64; ++k) Lsh[lane * LSTR + k] = a[k];
}

// ---------- multi-RHS triangular solve: N ILP chains share the L reads ----------
template <typename T, int N>
__device__ __forceinline__ void trisolveN(const T* __restrict__ Lsh, int lane,
                                          const float bv[N], float g[N]) {
  T x[N];
#pragma unroll
  for (int r = 0; r < N; ++r) x[r] = (T)bv[r];
  for (int j = 0; j < 63; ++j) {       // forward: L y = b (unit diag)
    T lij = Lsh[lane * LSTR + j];
#pragma unroll
    for (int r = 0; r < N; ++r) {
      T xj = rdl(x[r], j);
      if (lane > j) x[r] = x[r] - lij * xj;
    }
  }
  T d = Lsh[lane * LSTR + lane];
  if (d == (T)0) d = (T)1e-30;
#pragma unroll
  for (int r = 0; r < N; ++r) x[r] = x[r] / d;   // D z = y
  for (int j = 63; j > 0; --j) {       // backward: L^T w = z
    T lji = Lsh[j * LSTR + lane];
#pragma unroll
    for (int r = 0; r < N; ++r) {
      T xj = rdl(x[r], j);
      if (lane < j) x[r] = x[r] - lji * xj;
    }
  }
#pragma unroll
  for (int r = 0; r < N; ++r) g[r] = -(float)x[r];
}

// ---------- w = Vxx @ col, Vxx staged in LDS (symmetric -> rows as columns) ----------
__device__ __forceinline__ void matvec128_lds(const float* __restrict__ VxxS, float fcl, float fch,
                                              int lane, float& w0, float& w1) {
  w0 = 0.f; w1 = 0.f;
  const float* vrow = VxxS + 2 * lane;
#pragma unroll 8
  for (int c = 0; c < 64; ++c) {
    float s = rdl(fcl, c);
    float2 v = *(const float2*)(vrow + c * NXD);
    w0 = fmaf(v.x, s, w0); w1 = fmaf(v.y, s, w1);
  }
#pragma unroll 8
  for (int c = 0; c < 64; ++c) {
    float s = rdl(fch, c);
    float2 v = *(const float2*)(vrow + (64 + c) * NXD);
    w0 = fmaf(v.x, s, w0); w1 = fmaf(v.y, s, w1);
  }
}

__global__ void init_bar_kernel(unsigned* bar) {
  int i = threadIdx.x;                               // 256 threads x 4 = 1024 words
#pragma unroll
  for (int q = 0; q < 4; ++q) {
    int idx = i + 256 * q;
    unsigned v = (idx == 384) ? 0xFFFFFFFFu : 0u;    // leader sentinel at word 384
    __hip_atomic_store(bar + idx, v, __ATOMIC_RELAXED, __HIP_MEMORY_SCOPE_AGENT);
  }
}

__global__ __launch_bounds__(TPB, 1) void ilqr_main(
    const float* __restrict__ fx, const float* __restrict__ fa,
    const float* __restrict__ lx, const float* __restrict__ la,
    const float* __restrict__ lxx, const float* __restrict__ laa,
    const float* __restrict__ lax, float* __restrict__ out,
    float* __restrict__ wsf, unsigned* __restrict__ bar) {

  // ~98 KiB LDS -> 1 block/CU; P23 buffers alias dead P1 VxxS region
  __shared__ float SM[25088];
  float*  VxxS = SM;                       // [128][128]       (P1)
  float*  QaaS = SM;                       // 64*QSTR = 4160   (P23)
  float*  LfS  = SM + 4160;                // 64*LSTR = 4288
  float*  KS   = SM + 8448;                // 49*KSTR = 3332
  float*  QaxS = SM + 11780;               // 48*KSTR = 3264
  double* LdS  = (double*)(SM + 16384);    // 64*LSTR dbl (rare f64 path)
  __shared__ int flag64;
  __shared__ unsigned sRank;
  __shared__ int sAbort;

  const int tid = threadIdx.x;

  unsigned* arrive = bar + 0;
  unsigned* epoch  = bar + 128;
  unsigned* cnt    = bar + 256;  // [8] per-XCD census
  unsigned* leader = bar + 384;
  unsigned* abortW = bar + 512;

  // ======= CENSUS: elect 32 same-XCD workers (co-residency via cooperative launch) ===
  if (tid == 0) {
    unsigned xcd = ((unsigned)__builtin_amdgcn_s_getreg(HWREG_XCC_ID)) & 7u;
    unsigned slot = __hip_atomic_fetch_add(cnt + xcd, 1u, __ATOMIC_RELAXED, __HIP_MEMORY_SCOPE_AGENT);
    if (slot == NW - 1u) {                 // this XCD just mustered NW blocks
      unsigned exp = 0xFFFFFFFFu;
      __hip_atomic_compare_exchange_strong(leader, &exp, xcd, __ATOMIC_RELAXED,
                                           __ATOMIC_RELAXED, __HIP_MEMORY_SCOPE_AGENT);
    }
    unsigned L; unsigned it = 0;
    while ((L = __hip_atomic_load(leader, __ATOMIC_RELAXED, __HIP_MEMORY_SCOPE_AGENT)) == 0xFFFFFFFFu) {
      __builtin_amdgcn_s_sleep(8);
      if (++it > 2000000u) break;          // ~0.5s cap: visible failure, not hang
    }
    sRank = (L != 0xFFFFFFFFu && L == xcd && slot < NW) ? slot : 0xFFFFFFFFu;
  }
  __syncthreads();
  const unsigned rank = sRank;             // block-uniform
  if (rank >= NW) return;                  // non-workers exit; workers share one XCD
  const int b = (int)rank;

  const int w = tid >> 6;                  // 8 waves
  const int lane = tid & 63;
  const int ti = b >> 3, tj = b & 7;       // 4x8 grid of 32x16 Vxx tiles

  // workspace (plain cached accesses; coherence via XCD L2 + per-barrier L1 inv)
  float* Vxx  = wsf;               // 128*128, kept exactly symmetric
  float* Vx   = Vxx + 16384;       // 128
  float* QxxC = Vx + 128;          // 128*128, QxxC[j][i] = Qxx[i][j]
  float* QaxT = QxxC + 16384;      // 128*64,  QaxT[x][a] = Qax[a][x]
  float* QaaC = QaxT + 8192;       // 64*64,   QaaC[j][a] = Qaa[a][j]
  float* Qx   = QaaC + 4096;       // 128
  float* Qa   = Qx + 128;          // 64

  unsigned ep = 0;

  // ---- init carry: Vxx = lxx[T-1], Vx = lx[T-1] ----
  {
    const float* src = lxx + (size_t)(TSTEPS - 1) * NXD * NXD;
    int idx = b * TPB + tid;               // 32*512 = 16384 exactly
    Vxx[idx] = src[idx];
    if (b == 0 && tid < NXD) Vx[tid] = lx[(size_t)(TSTEPS - 1) * NXD + tid];
  }
  ++ep; if (!gbarL2(arrive, epoch, abortW, ep, &sAbort)) return;

  for (int t = TSTEPS - 1; t >= 0; --t) {
    const float* fxt  = fx  + (size_t)t * NXD * NXD;
    const float* fat  = fa  + (size_t)t * NXD * NAD;
    const float* lxt  = lx  + (size_t)t * NXD;
    const float* lat  = la  + (size_t)t * NAD;
    const float* lxxt = lxx + (size_t)t * NXD * NXD;
    const float* laat = laa + (size_t)t * NAD * NAD;
    const float* laxt = lax + (size_t)t * NAD * NXD;

    // ---- stage Vxx into LDS (plain float4 loads, fresh after L1 inv) ----
    {
      const float4* Vg4 = (const float4*)Vxx;
      float4* Vs4 = (float4*)VxxS;
#pragma unroll
      for (int q = 0; q < 8; ++q) Vs4[tid + TPB * q] = Vg4[tid + TPB * q];
    }
    __syncthreads();

    // ================= PHASE 1 =================
    if (w < 4) {
      const int j = 4 * b + w;             // fx column (128 total)
      float pf0 = fxt[lane * NXD + j];
      float pf1 = fxt[(64 + lane) * NXD + j];
      float w0, w1;
      matvec128_lds(VxxS, pf0, pf1, lane, w0, w1);   // w = Vxx @ fx[:,j]
      float q0 = lxxt[(size_t)(2 * lane) * NXD + j];
      float q1 = lxxt[(size_t)(2 * lane + 1) * NXD + j];
      float qa = laxt[lane * NXD + j];
#pragma unroll 4
      for (int r2 = 0; r2 < 32; ++r2) {
        float s0 = rdl(w0, r2), s1 = rdl(w1, r2);
        float t0 = s0 + rdl(pf0, 2 * r2);
        float t1 = s1 + rdl(pf0, 2 * r2 + 1);
        float2 f0 = *(const float2*)(fxt + (size_t)(2 * r2) * NXD + 2 * lane);
        float2 f1 = *(const float2*)(fxt + (size_t)(2 * r2 + 1) * NXD + 2 * lane);
        float g0 = fat[(2 * r2) * NAD + lane];
        float g1 = fat[(2 * r2 + 1) * NAD + lane];
        q0 = fmaf(f0.x, s0, q0); q1 = fmaf(f0.y, s0, q1);
        q0 = fmaf(f1.x, s1, q0); q1 = fmaf(f1.y, s1, q1);
        qa = fmaf(g0, t0, qa);   qa = fmaf(g1, t1, qa);
      }
#pragma unroll 4
      for (int r2 = 32; r2 < 64; ++r2) {
        float s0 = rdl(w0, r2), s1 = rdl(w1, r2);
        float t0 = s0 + rdl(pf1, 2 * r2 - 64);
        float t1 = s1 + rdl(pf1, 2 * r2 + 1 - 64);
        float2 f0 = *(const float2*)(fxt + (size_t)(2 * r2) * NXD + 2 * lane);
        float2 f1 = *(const float2*)(fxt + (size_t)(2 * r2 + 1) * NXD + 2 * lane);
        float g0 = fat[(2 * r2) * NAD + lane];
        float g1 = fat[(2 * r2 + 1) * NAD + lane];
        q0 = fmaf(f0.x, s0, q0); q1 = fmaf(f0.y, s0, q1);
        q0 = fmaf(f1.x, s1, q0); q1 = fmaf(f1.y, s1, q1);
        qa = fmaf(g0, t0, qa);   qa = fmaf(g1, t1, qa);
      }
      QxxC[(size_t)j * NXD + 2 * lane] = q0;
      QxxC[(size_t)j * NXD + 2 * lane + 1] = q1;
      QaxT[j * NAD + lane] = qa;
    } else if (w < 6) {
      const int j = 2 * b + (w - 4);       // fa column (64 total)
      float pf0 = fat[lane * NAD + j];
      float pf1 = fat[(64 + lane) * NAD + j];
      float w0, w1;
      matvec128_lds(VxxS, pf0, pf1, lane, w0, w1);   // w = Vxx @ fa[:,j]
      float qa = laat[lane * NAD + j];
#pragma unroll 4
      for (int r2 = 0; r2 < 32; ++r2) {
        float t0 = rdl(w0, r2) + rdl(pf0, 2 * r2);
        float t1 = rdl(w1, r2) + rdl(pf0, 2 * r2 + 1);
        float g0 = fat[(2 * r2) * NAD + lane];
        float g1 = fat[(2 * r2 + 1) * NAD + lane];
        qa = fmaf(g0, t0, qa); qa = fmaf(g1, t1, qa);
      }
#pragma unroll 4
      for (int r2 = 32; r2 < 64; ++r2) {
        float t0 = rdl(w0, r2) + rdl(pf1, 2 * r2 - 64);
        float t1 = rdl(w1, r2) + rdl(pf1, 2 * r2 + 1 - 64);
        float g0 = fat[(2 * r2) * NAD + lane];
        float g1 = fat[(2 * r2 + 1) * NAD + lane];
        qa = fmaf(g0, t0, qa); qa = fmaf(g1, t1, qa);
      }
      QaaC[j * NAD + lane] = qa;
    } else {
      // Qx / Qa rows: 6 per block (192 total)
      float pv0 = Vx[lane], pv1 = Vx[64 + lane];
#pragma unroll
      for (int q = 0; q < 3; ++q) {
        int rr = 6 * b + 3 * (w - 6) + q;
        float f0, f1;
        if (rr < NXD) { f0 = fxt[lane * NXD + rr]; f1 = fxt[(64 + lane) * NXD + rr]; }
        else { int aa = rr - NXD; f0 = fat[lane * NAD + aa]; f1 = fat[(64 + lane) * NAD + aa]; }
        float p = f0 * pv0 + f1 * pv1;
#pragma unroll
        for (int s = 1; s < 64; s <<= 1) p += __shfl_xor(p, s);
        if (lane == 0) {
          if (rr < NXD) Qx[rr] = lxt[rr] + p;
          else          Qa[rr - NXD] = lat[rr - NXD] + p;
        }
      }
    }
    ++ep; if (!gbarL2(arrive, epoch, abortW, ep, &sAbort)) return;

    // ================= PHASE 2+3: stage Qaa, factor, trisolve 49 RHS, update =====
#pragma unroll
    for (int q = 0; q < 8; ++q) {
      int idx = tid + TPB * q;             // 0..4095
      QaaS[(idx >> 6) * QSTR + (idx & 63)] = QaaC[idx];
    }
    // RHS slots: s<16 -> K col 16tj+s ; 16<=s<48 -> K col 32ti+(s-16) ; s==48 -> k
    float bv[7];
#pragma unroll
    for (int r = 0; r < 7; ++r) {
      int s = w + 8 * r;
      float v = 0.f;
      if (s < 49) {
        if (s == 48) v = Qa[lane];
        else {
          int c = (s < 16) ? (16 * tj + s) : (32 * ti + (s - 16));
          v = QaxT[(size_t)c * NAD + lane];
          QaxS[s * KSTR + lane] = v;
        }
      }
      bv[r] = v;
    }
    __syncthreads();
    if (w == 0) {
      float mmax = factor32(QaaS, lane, LfS);
      if (lane == 0) flag64 = !(mmax <= 64.0f);   // catches NaN too
    }
    __syncthreads();
    if (flag64 && w == 0) factor64(QaaS, lane, LdS);
    __syncthreads();
    {
      float g[7];
      if (!flag64) trisolveN<float, 7>(LfS, lane, bv, g);
      else         trisolveN<double, 7>(LdS, lane, bv, g);
#pragma unroll
      for (int r = 0; r < 7; ++r) {
        int s = w + 8 * r;
        if (s < 49) {
          KS[s * KSTR + lane] = g[r];
          bool writer = (s < 16 && ti == 0) || (s == 48 && b == 0);
          if (writer) {
            int m = (s < 16) ? (1 + 16 * tj + s) : 0;
            out[(size_t)t * NAD * GAINW + (size_t)lane * GAINW + m] = g[r];
          }
        }
      }
    }
    __syncthreads();

    // Vxx_n = sym(Qxx) + sym(Qax^T K); Vx_n = Qx + Qax^T k
    {
      int il = tid >> 4, jl = tid & 15;
      int i = 32 * ti + il, j = 16 * tj + jl;
      float d1 = 0.f, d2 = 0.f;
      const float* qi = QaxS + (16 + il) * KSTR;
      const float* qj = QaxS + jl * KSTR;
      const float* kj = KS + jl * KSTR;
      const float* ki = KS + (16 + il) * KSTR;
#pragma unroll 4
      for (int a4 = 0; a4 < 16; ++a4) {
        float4 A = *(const float4*)(qi + 4 * a4);
        float4 B = *(const float4*)(kj + 4 * a4);
        float4 C = *(const float4*)(qj + 4 * a4);
        float4 D = *(const float4*)(ki + 4 * a4);
        d1 = fmaf(A.x, B.x, d1); d1 = fmaf(A.y, B.y, d1);
        d1 = fmaf(A.z, B.z, d1); d1 = fmaf(A.w, B.w, d1);
        d2 = fmaf(C.x, D.x, d2); d2 = fmaf(C.y, D.y, d2);
        d2 = fmaf(C.z, D.z, d2); d2 = fmaf(C.w, D.w, d2);
      }
      // commutative adds -> mirror block writes bitwise-identical value at (j,i)
      float v = 0.5f * (QxxC[(size_t)j * NXD + i] + QxxC[(size_t)i * NXD + j])
              + 0.5f * (d1 + d2);
      Vxx[(size_t)i * NXD + j] = v;

      if (tj == 0 && jl == 0) {            // 4 blocks x 32 rows cover all 128
        float acc = 0.f;
        const float* k0 = KS + 48 * KSTR;
#pragma unroll 4
        for (int a4 = 0; a4 < 16; ++a4) {
          float4 A = *(const float4*)(qi + 4 * a4);
          float4 B = *(const float4*)(k0 + 4 * a4);
          acc = fmaf(A.x, B.x, acc); acc = fmaf(A.y, B.y, acc);
          acc = fmaf(A.z, B.z, acc); acc = fmaf(A.w, B.w, acc);
        }
        Vx[i] = Qx[i] + acc;
      }
    }
    ++ep; if (!gbarL2(arrive, epoch, abortW, ep, &sAbort)) return;
  }
}

extern "C" void kernel_launch(void* const* d_in, const int* in_sizes, int n_in,
                              void* d_out, int out_size, void* d_ws, size_t ws_size,
                              hipStream_t stream) {
  const float* fx  = (const float*)d_in[0];
  const float* fa  = (const float*)d_in[1];
  const float* lx  = (const float*)d_in[2];
  const float* la  = (const float*)d_in[3];
  const float* lxx = (const float*)d_in[4];
  const float* laa = (const float*)d_in[5];
  const float* lax = (const float*)d_in[6];
  float* out = (float*)d_out;

  unsigned* bar = (unsigned*)d_ws;                  // 1024 words, re-zeroed each call
  float* wsf = (float*)((char*)d_ws + 8192);

  hipLaunchKernelGGL(init_bar_kernel, dim3(1), dim3(256), 0, stream, bar);

  void* args[10];
  args[0] = (void*)&fx;  args[1] = (void*)&fa;  args[2] = (void*)&lx;
  args[3] = (void*)&la;  args[4] = (void*)&lxx; args[5] = (void*)&laa;
  args[6] = (void*)&lax; args[7] = (void*)&out; args[8] = (void*)&wsf;
  args[9] = (void*)&bar;
  hipLaunchCooperativeKernel((const void*)ilqr_main, dim3(256), dim3(TPB),
                             args, 0, stream);
}